// Round 1
// baseline (776.492 us; speedup 1.0000x reference)
//
#include <hip/hip_runtime.h>

#define BB 8
#define CC 512
#define NH 8
#define HD 64
#define HH 96
#define WW 96
#define AMP 3
#define KS 7
#define TH 16
#define TW 32
#define HALO_H (TH + 2*AMP)   // 22
#define HALO_W (TW + 2*AMP)   // 38
#define LDSW 41               // padded stride: 41 words -> <=2-way bank alias
#define DCH 8                 // d-planes staged per chunk

__global__ __launch_bounds__(256) void mov_kernel(const float* __restrict__ q,
                                                  const float* __restrict__ k,
                                                  float* __restrict__ out) {
    const int tid = threadIdx.x;          // 0..255
    const int tx  = tid & 15;             // 0..15  (w pairs)
    const int ty  = tid >> 4;             // 0..15  (h rows)
    const int tile = blockIdx.x;          // 0..17
    const int tw_i = tile % (WW / TW);    // 0..2
    const int th_i = tile / (WW / TW);    // 0..5
    const int n = blockIdx.y;
    const int b = blockIdx.z;
    const int h0 = th_i * TH;
    const int w0 = tw_i * TW;

    __shared__ float lk[DCH][HALO_H][LDSW];

    const int h = h0 + ty;
    const int w = w0 + 2 * tx;

    float acc0[KS * KS], acc1[KS * KS];
#pragma unroll
    for (int o = 0; o < KS * KS; ++o) { acc0[o] = 0.f; acc1[o] = 0.f; }

    const float scale = 0.125f;           // 64^-0.5
    const size_t plane = (size_t)HH * WW; // 9216
    const float* qbase = q + ((size_t)b * CC + n) * plane + (size_t)h * WW + w;
    const float* kbase = k + ((size_t)b * CC + n) * plane;

    for (int d0 = 0; d0 < HD; d0 += DCH) {
        __syncthreads();
        // ---- stage k halo for DCH planes ----
        for (int dd = 0; dd < DCH; ++dd) {
            const float* kp = kbase + (size_t)(d0 + dd) * NH * plane;
            for (int e = tid; e < HALO_H * HALO_W; e += 256) {
                int r  = e / HALO_W;
                int cc = e - r * HALO_W;
                int y = h0 + r - AMP;
                int x = w0 + cc - AMP;
                float v = 0.f;
                if ((unsigned)y < HH && (unsigned)x < WW)
                    v = kp[(size_t)y * WW + x];
                lk[dd][r][cc] = v;
            }
        }
        __syncthreads();
        // ---- accumulate 49 dots for the 2 pixels ----
#pragma unroll
        for (int dd = 0; dd < DCH; ++dd) {
            const float* qp = qbase + (size_t)(d0 + dd) * NH * plane;
            float q0 = qp[0] * scale;
            float q1 = qp[1] * scale;
#pragma unroll
            for (int i = 0; i < KS; ++i) {
                float kv[8];
#pragma unroll
                for (int t = 0; t < 8; ++t)
                    kv[t] = lk[dd][ty + i][2 * tx + t];
#pragma unroll
                for (int j = 0; j < KS; ++j) {
                    acc0[i * KS + j] += q0 * kv[j];
                    acc1[i * KS + j] += q1 * kv[j + 1];
                }
            }
        }
    }

    // ---- mask invalid offsets (reference: -1000 -> exp underflows to 0) ----
#pragma unroll
    for (int i = 0; i < KS; ++i) {
        bool vi = ((unsigned)(h + i - AMP) < HH);
#pragma unroll
        for (int j = 0; j < KS; ++j) {
            bool v0 = vi && ((unsigned)(w + j - AMP) < WW);
            bool v1 = vi && ((unsigned)(w + 1 + j - AMP) < WW);
            if (!v0) acc0[i * KS + j] = -1e30f;
            if (!v1) acc1[i * KS + j] = -1e30f;
        }
    }

    // ---- softmax over 49 offsets + expectation of (di, dj) ----
    float m0 = -1e30f, m1 = -1e30f;
#pragma unroll
    for (int o = 0; o < KS * KS; ++o) {
        m0 = fmaxf(m0, acc0[o]);
        m1 = fmaxf(m1, acc1[o]);
    }
    float l0 = 0.f, di0 = 0.f, dj0 = 0.f;
    float l1 = 0.f, di1 = 0.f, dj1 = 0.f;
#pragma unroll
    for (int i = 0; i < KS; ++i) {
#pragma unroll
        for (int j = 0; j < KS; ++j) {
            float e0 = __expf(acc0[i * KS + j] - m0);
            float e1 = __expf(acc1[i * KS + j] - m1);
            l0 += e0; l1 += e1;
            di0 += e0 * (float)(i - AMP);
            di1 += e1 * (float)(i - AMP);
            dj0 += e0 * (float)(j - AMP);
            dj1 += e1 * (float)(j - AMP);
        }
    }
    float inv0 = 1.0f / (l0 * (float)NH);  // /8 = head mean
    float inv1 = 1.0f / (l1 * (float)NH);

    float* o0 = out + ((size_t)b * 2 + 0) * plane + (size_t)h * WW + w;
    float* o1 = out + ((size_t)b * 2 + 1) * plane + (size_t)h * WW + w;
    atomicAdd(o0,     di0 * inv0);
    atomicAdd(o0 + 1, di1 * inv1);
    atomicAdd(o1,     dj0 * inv0);
    atomicAdd(o1 + 1, dj1 * inv1);
}

extern "C" void kernel_launch(void* const* d_in, const int* in_sizes, int n_in,
                              void* d_out, int out_size, void* d_ws, size_t ws_size,
                              hipStream_t stream) {
    const float* q = (const float*)d_in[0];
    const float* k = (const float*)d_in[1];
    float* out = (float*)d_out;

    hipMemsetAsync(out, 0, (size_t)out_size * sizeof(float), stream);

    dim3 grid(WW / TW * (HH / TH), NH, BB);   // (18, 8, 8)
    dim3 block(256);
    hipLaunchKernelGGL(mov_kernel, grid, block, 0, stream, q, k, out);
}